// Round 8
// baseline (190.575 us; speedup 1.0000x reference)
//
#include <hip/hip_runtime.h>
#include <hip/hip_bf16.h>
#include <stdint.h>

typedef short short8 __attribute__((ext_vector_type(8)));
typedef float f32x4  __attribute__((ext_vector_type(4)));
typedef unsigned short u16;

#define B_ROWS 4096
#define NEXP   8
#define IN_D   1024
#define OUT_D  1024

// ---------- fp32 -> bf16 (RNE) ----------
__device__ __forceinline__ u16 f2bf(float f) {
    uint32_t u = __float_as_uint(f);
    uint32_t r = (u + 0x7fffu + ((u >> 16) & 1u)) >> 16;
    return (u16)r;
}

// ---------- fused prep: W cvt (blocks 0..8191) + prescaled-A build (blocks 8192..12287) ----------
// A[k][b][i] = bf16(bw[b,k] * x[b,i])
#define W_CVT_BLOCKS 8192
__global__ __launch_bounds__(256) void prep(const float* __restrict__ x,
                                            const float* __restrict__ bwt,
                                            const float* __restrict__ wgt,
                                            u16* __restrict__ ab,
                                            u16* __restrict__ wb) {
    const int bid = blockIdx.x;
    if (bid < W_CVT_BLOCKS) {
        const int i = bid * 256 + threadIdx.x;
        float4 v = reinterpret_cast<const float4*>(wgt)[i];
        ushort4 o;
        o.x = f2bf(v.x); o.y = f2bf(v.y); o.z = f2bf(v.z); o.w = f2bf(v.w);
        reinterpret_cast<ushort4*>(wb)[i] = o;
    } else {
        const int b = bid - W_CVT_BLOCKS;        // row 0..4095
        const int i4 = threadIdx.x;              // 0..255 (1024 cols / 4)
        float4 v = reinterpret_cast<const float4*>(x)[(size_t)b * 256 + i4];
        float4 w0 = reinterpret_cast<const float4*>(bwt)[b * 2];
        float4 w1 = reinterpret_cast<const float4*>(bwt)[b * 2 + 1];
        float wk[8] = {w0.x, w0.y, w0.z, w0.w, w1.x, w1.y, w1.z, w1.w};
        #pragma unroll
        for (int k = 0; k < NEXP; ++k) {
            ushort4 o;
            o.x = f2bf(wk[k] * v.x); o.y = f2bf(wk[k] * v.y);
            o.z = f2bf(wk[k] * v.z); o.w = f2bf(wk[k] * v.w);
            reinterpret_cast<ushort4*>(ab)[((size_t)k * B_ROWS + b) * 256 + i4] = o;
        }
    }
}

// ---------- async global->LDS, 16B/lane; LDS dest = wave-uniform off + lane*16 (HW) ----------
__device__ __forceinline__ void glds16(const u16* g, u16* lds_base, uint32_t off) {
    auto gp = (const __attribute__((address_space(1))) void*)(uintptr_t)(g);
    auto lp = (__attribute__((address_space(3))) void*)(uintptr_t)((const char*)lds_base + off);
    __builtin_amdgcn_global_load_lds(gp, lp, 16, 0, 0);
}

// ============ 256x256 8-phase GEMM (round-4 verbatim; known 71.7 us) ============
#define PHASE(BUF, QM, QN, LOADA, STAGE_STMT)                                     \
  {                                                                               \
    asm volatile("s_waitcnt vmcnt(6)" ::: "memory");                              \
    if (LOADA) {                                                                  \
      _Pragma("unroll") for (int mi = 0; mi < 4; ++mi)                            \
        _Pragma("unroll") for (int ks = 0; ks < 2; ++ks)                          \
          af[mi][ks] = *(const short8*)(ldsc + (BUF)*65536 + (QM)*16384 +         \
                                        aRowB + mi*2048 + cXor[ks]);              \
    }                                                                             \
    _Pragma("unroll") for (int ni = 0; ni < 2; ++ni)                              \
      _Pragma("unroll") for (int ks = 0; ks < 2; ++ks)                            \
        bf[ni][ks] = *(const short8*)(ldsc + (BUF)*65536 + 32768 + (QN)*16384 +   \
                                      bRowB + ni*2048 + cXor[ks]);                \
    STAGE_STMT;                                                                   \
    __builtin_amdgcn_s_barrier();                                                 \
    __builtin_amdgcn_s_setprio(1);                                                \
    _Pragma("unroll") for (int mi = 0; mi < 4; ++mi)                              \
      _Pragma("unroll") for (int ni = 0; ni < 2; ++ni) {                          \
        acc[QM][QN][mi][ni] = __builtin_amdgcn_mfma_f32_16x16x32_bf16(            \
            af[mi][0], bf[ni][0], acc[QM][QN][mi][ni], 0, 0, 0);                  \
        acc[QM][QN][mi][ni] = __builtin_amdgcn_mfma_f32_16x16x32_bf16(            \
            af[mi][1], bf[ni][1], acc[QM][QN][mi][ni], 0, 0, 0);                  \
      }                                                                           \
    __builtin_amdgcn_s_setprio(0);                                                \
    __builtin_amdgcn_s_barrier();                                                 \
  }

__global__ __launch_bounds__(512, 2) void moe_gemm8(
    const u16* __restrict__ Ab,   // [8][4096][1024] bf16 (pre-scaled by blend weights)
    const u16* __restrict__ Wb,   // [8][1024][1024] bf16 (k,o,i)
    float* __restrict__ parts,    // [nz-1][4096][1024] fp32 partials
    float* __restrict__ out,      // last slice target
    int epb, int nz)
{
    __shared__ __align__(16) u16 lds[65536];  // 128 KiB

    // T1 chunked XCD swizzle (nwg % 8 == 0 for nz in {1,2,4})
    const int nwg = gridDim.x;
    const int cpx = nwg >> 3;
    const int id  = blockIdx.x;
    const int swz = (id & 7) * cpx + (id >> 3);
    const int bz  = swz >> 6;             // 64 tiles (16x4) per z-slice
    const int rem = swz & 63;
    const int bm_g = (rem >> 2) * 256;
    const int bn_g = (rem & 3) * 256;

    const int tid  = threadIdx.x;
    const int lane = tid & 63, wid = tid >> 6;
    const int wm = wid >> 2, wn = wid & 3;        // 2x4 wave grid
    const int lr = lane & 15, lg = lane >> 4;

    const int nt   = epb << 4;   // K-tiles per block (BK=64)
    const int ntm1 = nt - 1;
    const int nit  = nt >> 1;

    // staging geometry: half-tile = 128 rows x 64 cols; chunk swizzle cr^=(row&7)
    const int row0   = wid * 8 + (lane >> 3);
    const int colOff = ((lane & 7) ^ (lane >> 3)) * 8;

    // read geometry (same involution on ds_read side)
    const char* ldsc = (const char*)lds;
    const int aRowB = (wm * 64 + lr) * 128;
    const int bRowB = (wn * 32 + lr) * 128;
    int cXor[2];
    cXor[0] = (lg * 16) ^ ((lr & 7) << 4);
    cXor[1] = (64 + lg * 16) ^ ((lr & 7) << 4);

    auto STAGE = [&](int t, int isB, int h, int buf) {
        const int kexp = bz * epb + (t >> 4);
        const int i0 = (t & 15) << 6;
        const u16* gp = isB
            ? Wb + ((size_t)kexp * OUT_D + bn_g + h * 128 + row0) * IN_D + i0 + colOff
            : Ab + ((size_t)kexp * B_ROWS + bm_g + h * 128 + row0) * IN_D + i0 + colOff;
        const uint32_t l0 = (uint32_t)((buf << 16) + (isB << 15) + (h << 14) + (wid << 10));
        glds16(gp, lds, l0);
        glds16(gp + (size_t)64 * IN_D, lds, l0 + 8192);
    };

    f32x4 acc[2][2][4][2];
    #pragma unroll
    for (int a = 0; a < 2; ++a)
      #pragma unroll
      for (int b = 0; b < 2; ++b)
        #pragma unroll
        for (int c = 0; c < 4; ++c)
          #pragma unroll
          for (int d = 0; d < 2; ++d)
            acc[a][b][c][d] = (f32x4){0.f, 0.f, 0.f, 0.f};

    short8 af[4][2], bf[2][2];

    // prologue: AL0,BL0,BH0,AH0,AL1,BL1 then full drain
    STAGE(0, 0, 0, 0);
    STAGE(0, 1, 0, 0);
    STAGE(0, 1, 1, 0);
    STAGE(0, 0, 1, 0);
    STAGE(1, 0, 0, 1);
    STAGE(1, 1, 0, 1);
    asm volatile("s_waitcnt vmcnt(0)" ::: "memory");
    __builtin_amdgcn_s_barrier();

    for (int m = 0; m < nit; ++m) {
        const int t1 = 2 * m + 1;            // buf1 tile (t0=2m in buf0)
        const int t2 = (t1 + 1) & ntm1;      // wraps in tail (uniform vmcnt counts)
        const int t3 = (t1 + 2) & ntm1;
        PHASE(0, 0, 0, 1, STAGE(t1, 1, 1, 1));   // ph1: BH(t1)->buf1
        PHASE(0, 0, 1, 0, STAGE(t1, 0, 1, 1));   // ph2: AH(t1)->buf1
        PHASE(0, 1, 0, 1, STAGE(t2, 0, 0, 0));   // ph3: AL(t2)->buf0
        PHASE(0, 1, 1, 0, STAGE(t2, 1, 0, 0));   // ph4: BL(t2)->buf0
        PHASE(1, 0, 0, 1, STAGE(t2, 1, 1, 0));   // ph5: BH(t2)->buf0
        PHASE(1, 0, 1, 0, STAGE(t2, 0, 1, 0));   // ph6: AH(t2)->buf0
        PHASE(1, 1, 0, 1, STAGE(t3, 0, 0, 1));   // ph7: AL(t3)->buf1
        PHASE(1, 1, 1, 0, STAGE(t3, 1, 0, 1));   // ph8: BL(t3)->buf1
    }

    // epilogue: fp32 stores (r4-proven), nontemporal (write-once; keep L2 for A/B)
    float* op = (bz == nz - 1) ? out : parts + (size_t)bz * B_ROWS * OUT_D;
    #pragma unroll
    for (int qm = 0; qm < 2; ++qm)
      #pragma unroll
      for (int mi = 0; mi < 4; ++mi)
        #pragma unroll
        for (int qn = 0; qn < 2; ++qn)
          #pragma unroll
          for (int ni = 0; ni < 2; ++ni)
            #pragma unroll
            for (int r = 0; r < 4; ++r) {
                const int grow = bm_g + qm * 128 + wm * 64 + mi * 16 + lg * 4 + r;
                const int gcol = bn_g + qn * 128 + wn * 32 + ni * 16 + lr;
                __builtin_nontemporal_store(acc[qm][qn][mi][ni][r],
                                            op + (size_t)grow * OUT_D + gcol);
            }
}

// ---------- finalize: out += partials + bw@bias ----------
__global__ __launch_bounds__(256) void reduce_bias(
    const float* __restrict__ parts, const float* __restrict__ bwt,
    const float* __restrict__ bias, float* __restrict__ out, int np)
{
    const int i4 = blockIdx.x * 256 + threadIdx.x;
    const size_t total = (size_t)B_ROWS * OUT_D;
    const size_t base = (size_t)i4 * 4;
    if (base >= total) return;
    const int brow = (int)(base >> 10);
    const int o = (int)(base & 1023);

    // nontemporal via clang ext-vector (f32x4), NOT HIP_vector_type float4
    f32x4 s = __builtin_nontemporal_load(reinterpret_cast<const f32x4*>(out + base));
    for (int z = 0; z < np; ++z) {
        f32x4 p = __builtin_nontemporal_load(
            reinterpret_cast<const f32x4*>(parts + (size_t)z * total + base));
        s += p;
    }
    #pragma unroll
    for (int k = 0; k < NEXP; ++k) {
        const float w = bwt[brow * NEXP + k];
        const f32x4 bb = *reinterpret_cast<const f32x4*>(bias + k * OUT_D + o);
        s += w * bb;
    }
    __builtin_nontemporal_store(s, reinterpret_cast<f32x4*>(out + base));
}

// ---------- emergency fallback (ws too small): fp32 direct ----------
__global__ __launch_bounds__(256) void naive_moe(
    const float* __restrict__ x, const float* __restrict__ bwt,
    const float* __restrict__ wgt, const float* __restrict__ bias,
    float* __restrict__ out)
{
    __shared__ float xs[IN_D];
    const int brow = blockIdx.x;
    const int o = blockIdx.y * 256 + threadIdx.x;
    for (int i = threadIdx.x; i < IN_D; i += 256) xs[i] = x[(size_t)brow * IN_D + i];
    __syncthreads();
    float acc = 0.f;
    for (int k = 0; k < NEXP; ++k) {
        const float* wr = wgt + ((size_t)k * OUT_D + o) * IN_D;
        float d = 0.f;
        for (int i = 0; i < IN_D; ++i) d += xs[i] * wr[i];
        acc += bwt[brow * NEXP + k] * (d + bias[k * OUT_D + o]);
    }
    out[(size_t)brow * OUT_D + o] = acc;
}

extern "C" void kernel_launch(void* const* d_in, const int* in_sizes, int n_in,
                              void* d_out, int out_size, void* d_ws, size_t ws_size,
                              hipStream_t stream) {
    const float* x    = (const float*)d_in[0];
    const float* bwt  = (const float*)d_in[1];
    const float* wgt  = (const float*)d_in[2];
    const float* bias = (const float*)d_in[3];
    float* out = (float*)d_out;

    const size_t a_bytes    = (size_t)NEXP * B_ROWS * IN_D * 2;  // 64 MiB
    const size_t w_bytes    = (size_t)NEXP * OUT_D * IN_D * 2;   // 16 MiB
    const size_t part_bytes = (size_t)B_ROWS * OUT_D * 4;        // 16 MiB (fp32)

    if (ws_size < a_bytes + w_bytes) {
        naive_moe<<<dim3(B_ROWS, OUT_D / 256), 256, 0, stream>>>(x, bwt, wgt, bias, out);
        return;
    }

    int nz = 1;
    if      (ws_size >= a_bytes + w_bytes + 3 * part_bytes) nz = 4;  // 128 MiB total
    else if (ws_size >= a_bytes + w_bytes + 1 * part_bytes) nz = 2;

    u16* ab = (u16*)d_ws;
    u16* wb = (u16*)((char*)d_ws + a_bytes);
    float* parts = (float*)((char*)d_ws + a_bytes + w_bytes);

    prep<<<W_CVT_BLOCKS + B_ROWS, 256, 0, stream>>>(x, bwt, wgt, ab, wb);

    moe_gemm8<<<64 * nz, 512, 0, stream>>>(ab, wb, parts, out, NEXP / nz, nz);

    reduce_bias<<<(B_ROWS * OUT_D / 4 + 255) / 256, 256, 0, stream>>>(
        parts, bwt, bias, out, nz - 1);
}

// Round 9
// 181.380 us; speedup vs baseline: 1.0507x; 1.0507x over previous
//
#include <hip/hip_runtime.h>
#include <hip/hip_bf16.h>
#include <stdint.h>

typedef short short8 __attribute__((ext_vector_type(8)));
typedef float f32x4  __attribute__((ext_vector_type(4)));
typedef unsigned short u16;

#define B_ROWS 4096
#define NEXP   8
#define IN_D   1024
#define OUT_D  1024

// ---------- fp32 -> bf16 (RNE) ----------
__device__ __forceinline__ u16 f2bf(float f) {
    uint32_t u = __float_as_uint(f);
    uint32_t r = (u + 0x7fffu + ((u >> 16) & 1u)) >> 16;
    return (u16)r;
}

// ---------- fused prep: W cvt (blocks 0..8191) + prescaled-A build (blocks 8192..12287) ----------
// A[k][b][i] = bf16(bw[b,k] * x[b,i])
#define W_CVT_BLOCKS 8192
__global__ __launch_bounds__(256) void prep(const float* __restrict__ x,
                                            const float* __restrict__ bwt,
                                            const float* __restrict__ wgt,
                                            u16* __restrict__ ab,
                                            u16* __restrict__ wb) {
    const int bid = blockIdx.x;
    if (bid < W_CVT_BLOCKS) {
        const int i = bid * 256 + threadIdx.x;
        float4 v = reinterpret_cast<const float4*>(wgt)[i];
        ushort4 o;
        o.x = f2bf(v.x); o.y = f2bf(v.y); o.z = f2bf(v.z); o.w = f2bf(v.w);
        reinterpret_cast<ushort4*>(wb)[i] = o;
    } else {
        const int b = bid - W_CVT_BLOCKS;        // row 0..4095
        const int i4 = threadIdx.x;              // 0..255 (1024 cols / 4)
        float4 v = reinterpret_cast<const float4*>(x)[(size_t)b * 256 + i4];
        float4 w0 = reinterpret_cast<const float4*>(bwt)[b * 2];
        float4 w1 = reinterpret_cast<const float4*>(bwt)[b * 2 + 1];
        float wk[8] = {w0.x, w0.y, w0.z, w0.w, w1.x, w1.y, w1.z, w1.w};
        #pragma unroll
        for (int k = 0; k < NEXP; ++k) {
            ushort4 o;
            o.x = f2bf(wk[k] * v.x); o.y = f2bf(wk[k] * v.y);
            o.z = f2bf(wk[k] * v.z); o.w = f2bf(wk[k] * v.w);
            reinterpret_cast<ushort4*>(ab)[((size_t)k * B_ROWS + b) * 256 + i4] = o;
        }
    }
}

// ---------- async global->LDS, 16B/lane; LDS dest = wave-uniform off + lane*16 (HW) ----------
__device__ __forceinline__ void glds16(const u16* g, u16* lds_base, uint32_t off) {
    auto gp = (const __attribute__((address_space(1))) void*)(uintptr_t)(g);
    auto lp = (__attribute__((address_space(3))) void*)(uintptr_t)((const char*)lds_base + off);
    __builtin_amdgcn_global_load_lds(gp, lp, 16, 0, 0);
}

// ============ 256x128 4-phase GEMM, nz=2 (K=4096/block, 32 iters) ============
// LDS per buf (49152 B): A-half qm*16384 (2 x 128rows x 64cols bf16), B at +32768
// (one 128x64 half). Rotation: P1:AH(t1) P2:AL(t2),B(t2) P3:AH(t2) P4:AL(t3),B(t3).
// Every half staged one phase after its last ds_read; uniform vmcnt(6) drains the
// needed stage at every phase (loads/phase [2,4,2,4], queue 8-10 -> wait-to-6).
// B fragments (bf) are loaded in P1/P3 and reused in P2/P4 (same B for both qm).
#define PHASE(BUF, QM, LOADB, STAGE_STMT)                                         \
  {                                                                               \
    asm volatile("s_waitcnt vmcnt(6)" ::: "memory");                              \
    _Pragma("unroll") for (int mi = 0; mi < 4; ++mi)                              \
      _Pragma("unroll") for (int ks = 0; ks < 2; ++ks)                            \
        af[mi][ks] = *(const short8*)(ldsc + (BUF)*49152 + (QM)*16384 +           \
                                      aRowB + mi*2048 + cXor[ks]);                \
    if (LOADB) {                                                                  \
      _Pragma("unroll") for (int ni = 0; ni < 2; ++ni)                            \
        _Pragma("unroll") for (int ks = 0; ks < 2; ++ks)                          \
          bf[ni][ks] = *(const short8*)(ldsc + (BUF)*49152 + 32768 +              \
                                        bRowB + ni*2048 + cXor[ks]);              \
    }                                                                             \
    STAGE_STMT;                                                                   \
    __builtin_amdgcn_s_barrier();                                                 \
    __builtin_amdgcn_s_setprio(1);                                                \
    _Pragma("unroll") for (int mi = 0; mi < 4; ++mi)                              \
      _Pragma("unroll") for (int ni = 0; ni < 2; ++ni) {                          \
        acc[QM][mi][ni] = __builtin_amdgcn_mfma_f32_16x16x32_bf16(                \
            af[mi][0], bf[ni][0], acc[QM][mi][ni], 0, 0, 0);                      \
        acc[QM][mi][ni] = __builtin_amdgcn_mfma_f32_16x16x32_bf16(                \
            af[mi][1], bf[ni][1], acc[QM][mi][ni], 0, 0, 0);                      \
      }                                                                           \
    __builtin_amdgcn_s_setprio(0);                                                \
    __builtin_amdgcn_s_barrier();                                                 \
  }

__global__ __launch_bounds__(512, 2) void moe_gemm4p(
    const u16* __restrict__ Ab,   // [8][4096][1024] bf16 (pre-scaled by blend weights)
    const u16* __restrict__ Wb,   // [8][1024][1024] bf16 (k,o,i)
    float* __restrict__ parts,    // [1][4096][1024] fp32 partial (slice 0)
    float* __restrict__ out,      // slice 1 target
    int epb)                      // experts per slice = 4
{
    __shared__ __align__(16) u16 lds[49152];  // 96 KiB

    // T1 chunked XCD swizzle (nwg = 256, cpx = 32)
    const int nwg = gridDim.x;
    const int cpx = nwg >> 3;
    const int id  = blockIdx.x;
    const int swz = (id & 7) * cpx + (id >> 3);
    const int bz  = swz >> 7;             // 128 spatial tiles per slice
    const int rem = swz & 127;
    const int bm_g = (rem >> 3) * 256;    // 16 row tiles
    const int bn_g = (rem & 7) * 128;     // 8 col tiles

    const int tid  = threadIdx.x;
    const int lane = tid & 63, wid = tid >> 6;
    const int wm = wid >> 2, wn = wid & 3;        // 2x4 wave grid; wave out = 128x32
    const int lr = lane & 15, lg = lane >> 4;

    const int nt   = epb << 4;   // 64 K-tiles per block (BK=64)
    const int ntm1 = nt - 1;
    const int nit  = nt >> 1;    // 32

    // staging geometry: half-tile = 128 rows x 64 cols; chunk swizzle cr^=(row&7)
    const int row0   = wid * 8 + (lane >> 3);
    const int colOff = ((lane & 7) ^ (lane >> 3)) * 8;

    // read geometry (same involution on ds_read side)
    const char* ldsc = (const char*)lds;
    const int aRowB = (wm * 64 + lr) * 128;
    const int bRowB = (wn * 32 + lr) * 128;
    int cXor[2];
    cXor[0] = (lg * 16) ^ ((lr & 7) << 4);
    cXor[1] = (64 + lg * 16) ^ ((lr & 7) << 4);

    auto STAGE = [&](int t, int isB, int h, int buf) {
        const int kexp = bz * epb + (t >> 4);
        const int i0 = (t & 15) << 6;
        const u16* gp = isB
            ? Wb + ((size_t)kexp * OUT_D + bn_g + row0) * IN_D + i0 + colOff
            : Ab + ((size_t)kexp * B_ROWS + bm_g + h * 128 + row0) * IN_D + i0 + colOff;
        const uint32_t l0 = (uint32_t)(buf * 49152 + (isB ? 32768 : h * 16384) + (wid << 10));
        glds16(gp, lds, l0);
        glds16(gp + (size_t)64 * IN_D, lds, l0 + 8192);
    };

    f32x4 acc[2][4][2];
    #pragma unroll
    for (int a = 0; a < 2; ++a)
      #pragma unroll
      for (int c = 0; c < 4; ++c)
        #pragma unroll
        for (int d = 0; d < 2; ++d)
          acc[a][c][d] = (f32x4){0.f, 0.f, 0.f, 0.f};

    short8 af[4][2], bf[2][2];

    // prologue: AL0,AH0,B0 -> buf0; AL1,B1 -> buf1; full drain
    STAGE(0, 0, 0, 0);
    STAGE(0, 0, 1, 0);
    STAGE(0, 1, 0, 0);
    STAGE(1, 0, 0, 1);
    STAGE(1, 1, 0, 1);
    asm volatile("s_waitcnt vmcnt(0)" ::: "memory");
    __builtin_amdgcn_s_barrier();

    for (int m = 0; m < nit; ++m) {
        const int t1 = 2 * m + 1;            // buf1 tile (t0=2m in buf0)
        const int t2 = (t1 + 1) & ntm1;      // wraps in tail (uniform vmcnt counts)
        const int t3 = (t1 + 2) & ntm1;
        PHASE(0, 0, 1, STAGE(t1, 0, 1, 1));                       // P1: AH(t1)->buf1
        PHASE(0, 1, 0, { STAGE(t2, 0, 0, 0); STAGE(t2, 1, 0, 0); }); // P2: AL(t2),B(t2)->buf0
        PHASE(1, 0, 1, STAGE(t2, 0, 1, 0));                       // P3: AH(t2)->buf0
        PHASE(1, 1, 0, { STAGE(t3, 0, 0, 1); STAGE(t3, 1, 0, 1); }); // P4: AL(t3),B(t3)->buf1
    }

    // epilogue: plain fp32 stores (r4-proven; nontemporal regressed in r8)
    float* op = (bz == 1) ? out : parts;
    #pragma unroll
    for (int qm = 0; qm < 2; ++qm)
      #pragma unroll
      for (int mi = 0; mi < 4; ++mi)
        #pragma unroll
        for (int ni = 0; ni < 2; ++ni)
          #pragma unroll
          for (int r = 0; r < 4; ++r) {
              const int grow = bm_g + qm * 128 + wm * 64 + mi * 16 + lg * 4 + r;
              const int gcol = bn_g + wn * 32 + ni * 16 + lr;
              op[(size_t)grow * OUT_D + gcol] = acc[qm][mi][ni][r];
          }
}

// ---------- finalize: out += partial + bw@bias ----------
__global__ __launch_bounds__(256) void reduce_bias(
    const float* __restrict__ parts, const float* __restrict__ bwt,
    const float* __restrict__ bias, float* __restrict__ out)
{
    const int i4 = blockIdx.x * 256 + threadIdx.x;
    const size_t total = (size_t)B_ROWS * OUT_D;
    const size_t base = (size_t)i4 * 4;
    if (base >= total) return;
    const int brow = (int)(base >> 10);
    const int o = (int)(base & 1023);

    float4 s = *reinterpret_cast<const float4*>(out + base);
    float4 p = *reinterpret_cast<const float4*>(parts + base);
    s.x += p.x; s.y += p.y; s.z += p.z; s.w += p.w;
    #pragma unroll
    for (int k = 0; k < NEXP; ++k) {
        const float w = bwt[brow * NEXP + k];
        float4 bb = *reinterpret_cast<const float4*>(bias + k * OUT_D + o);
        s.x += w * bb.x; s.y += w * bb.y; s.z += w * bb.z; s.w += w * bb.w;
    }
    *reinterpret_cast<float4*>(out + base) = s;
}

// ---------- emergency fallback (ws too small): fp32 direct ----------
__global__ __launch_bounds__(256) void naive_moe(
    const float* __restrict__ x, const float* __restrict__ bwt,
    const float* __restrict__ wgt, const float* __restrict__ bias,
    float* __restrict__ out)
{
    __shared__ float xs[IN_D];
    const int brow = blockIdx.x;
    const int o = blockIdx.y * 256 + threadIdx.x;
    for (int i = threadIdx.x; i < IN_D; i += 256) xs[i] = x[(size_t)brow * IN_D + i];
    __syncthreads();
    float acc = 0.f;
    for (int k = 0; k < NEXP; ++k) {
        const float* wr = wgt + ((size_t)k * OUT_D + o) * IN_D;
        float d = 0.f;
        for (int i = 0; i < IN_D; ++i) d += xs[i] * wr[i];
        acc += bwt[brow * NEXP + k] * (d + bias[k * OUT_D + o]);
    }
    out[(size_t)brow * OUT_D + o] = acc;
}

extern "C" void kernel_launch(void* const* d_in, const int* in_sizes, int n_in,
                              void* d_out, int out_size, void* d_ws, size_t ws_size,
                              hipStream_t stream) {
    const float* x    = (const float*)d_in[0];
    const float* bwt  = (const float*)d_in[1];
    const float* wgt  = (const float*)d_in[2];
    const float* bias = (const float*)d_in[3];
    float* out = (float*)d_out;

    const size_t a_bytes    = (size_t)NEXP * B_ROWS * IN_D * 2;  // 64 MiB
    const size_t w_bytes    = (size_t)NEXP * OUT_D * IN_D * 2;   // 16 MiB
    const size_t part_bytes = (size_t)B_ROWS * OUT_D * 4;        // 16 MiB (fp32)

    if (ws_size < a_bytes + w_bytes + part_bytes) {   // 96 MiB needed
        naive_moe<<<dim3(B_ROWS, OUT_D / 256), 256, 0, stream>>>(x, bwt, wgt, bias, out);
        return;
    }

    u16* ab = (u16*)d_ws;
    u16* wb = (u16*)((char*)d_ws + a_bytes);
    float* parts = (float*)((char*)d_ws + a_bytes + w_bytes);

    prep<<<W_CVT_BLOCKS + B_ROWS, 256, 0, stream>>>(x, bwt, wgt, ab, wb);

    moe_gemm4p<<<256, 512, 0, stream>>>(ab, wb, parts, out, NEXP / 2);

    reduce_bias<<<(B_ROWS * OUT_D / 4 + 255) / 256, 256, 0, stream>>>(
        parts, bwt, bias, out);
}